// Round 2
// baseline (1104.699 us; speedup 1.0000x reference)
//
#include <hip/hip_runtime.h>
#include <hip/hip_bf16.h>

// Problem constants (fixed by the reference).
constexpr int N_NODES = 100000;
constexpr int N_EDGES = 1600000;
constexpr int IN_C  = 128;
constexpr int HID_C = 64;   // == OUT_C
constexpr int NUM_CLASSES = 40;

// ---------------------------------------------------------------- degree ----
__global__ void deg_init_kernel(unsigned* __restrict__ deg) {
    int i = blockIdx.x * blockDim.x + threadIdx.x;
    if (i < N_NODES) deg[i] = 1u;   // self-loop
}

__global__ void deg_count_kernel(const int* __restrict__ dst, unsigned* __restrict__ deg) {
    int e = blockIdx.x * blockDim.x + threadIdx.x;
    if (e < N_EDGES) atomicAdd(&deg[dst[e]], 1u);
}

__global__ void inv_from_deg_kernel(float* __restrict__ buf) {
    int i = blockIdx.x * blockDim.x + threadIdx.x;
    if (i >= N_NODES) return;
    unsigned d = ((const unsigned*)buf)[i];
    buf[i] = rsqrtf((float)d);
}

// -------------------------------------------------- GEMM (X@W)*inv -> out ---
// X: [n, K] f32, W: [K, 64] f32 row-major, out: [n, 64] f32 (scaled by inv).
template <int K>
__global__ void gemm_scale_kernel(const float* __restrict__ X,
                                  const float* __restrict__ W,
                                  const float* __restrict__ inv,
                                  float* __restrict__ out, int n) {
    constexpr int C = 64;
    constexpr int ROWS = 4;           // blockDim = 256 = ROWS * C
    __shared__ float Ws[K][C];
    __shared__ float Xs[ROWS][K];
    int tid = threadIdx.x;
    for (int i = tid; i < K * C; i += 256) Ws[i / C][i % C] = W[i];
    int n0 = blockIdx.x * ROWS;
    for (int i = tid; i < ROWS * K; i += 256) {
        int r = i / K, k = i % K;
        int nn = n0 + r;
        Xs[r][k] = (nn < n) ? X[(size_t)nn * K + k] : 0.f;
    }
    __syncthreads();
    int r = tid >> 6;     // 0..3
    int c = tid & 63;
    int nn = n0 + r;
    if (nn >= n) return;
    float sum = 0.f;
#pragma unroll 8
    for (int k = 0; k < K; ++k) sum += Xs[r][k] * Ws[k][c];
    out[(size_t)nn * C + c] = sum * inv[nn];
}

// ------------------------------------------------------- edge scatter-add ---
// acc[dst] += hs[src]  (hs already scaled by inv[src]); one wave per edge.
__global__ void agg_kernel(const int* __restrict__ src, const int* __restrict__ dst,
                           const float* __restrict__ hs, float* __restrict__ acc) {
    int e = blockIdx.x * 4 + (threadIdx.x >> 6);
    if (e >= N_EDGES) return;
    int c = threadIdx.x & 63;
    int s = src[e];
    int d = dst[e];
    atomicAdd(&acc[(size_t)d * 64 + c], hs[(size_t)s * 64 + c]);
}

// -------------------------------------- out = relu(inv*(acc + hs) + bias) ---
__global__ void finalize_kernel(float* __restrict__ acc, const float* __restrict__ hs,
                                const float* __restrict__ inv,
                                const float* __restrict__ bias) {
    int idx = blockIdx.x * blockDim.x + threadIdx.x;
    if (idx >= N_NODES * 64) return;
    int nn = idx >> 6;
    int c  = idx & 63;
    float v = inv[nn] * (acc[idx] + hs[idx]) + bias[c];
    acc[idx] = fmaxf(v, 0.f);
}

// ---------------------------------------------- final classifier GEMM -------
// out[n, 40] f32 = H[n, 64] @ Wf[64, 40] + bf
__global__ void final_gemm_kernel(const float* __restrict__ H,
                                  const float* __restrict__ Wf,
                                  const float* __restrict__ bfv,
                                  float* __restrict__ out, int n) {
    constexpr int C = 64, J = 40, ROWS = 8;   // blockDim = 320 = ROWS * J
    __shared__ float Ws[C][J];
    __shared__ float Hs[ROWS][C];
    int tid = threadIdx.x;
    for (int i = tid; i < C * J; i += 320) Ws[i / J][i % J] = Wf[i];
    int n0 = blockIdx.x * ROWS;
    for (int i = tid; i < ROWS * C; i += 320) {
        int r = i / C, c = i % C;
        int nn = n0 + r;
        Hs[r][c] = (nn < n) ? H[(size_t)nn * C + c] : 0.f;
    }
    __syncthreads();
    int r = tid / J, j = tid % J;
    int nn = n0 + r;
    if (nn >= n) return;
    float sum = bfv[j];
#pragma unroll
    for (int c = 0; c < C; ++c) sum += Hs[r][c] * Ws[c][j];
    out[(size_t)nn * J + j] = sum;
}

// ---------------------------------------------------------------- launch ----
extern "C" void kernel_launch(void* const* d_in, const int* in_sizes, int n_in,
                              void* d_out, int out_size, void* d_ws, size_t ws_size,
                              hipStream_t stream) {
    const float* x  = (const float*)d_in[0];
    const int*   ei = (const int*)d_in[1];
    const float* W1 = (const float*)d_in[2];
    const float* b1 = (const float*)d_in[3];
    const float* W2 = (const float*)d_in[4];
    const float* b2 = (const float*)d_in[5];
    const float* Wf = (const float*)d_in[6];
    const float* bf = (const float*)d_in[7];
    float* out = (float*)d_out;

    const int* src = ei;            // edge_index[0, :]
    const int* dst = ei + N_EDGES;  // edge_index[1, :]

    // Workspace layout: inv (N f32, padded to 512 KB) | A (N*64 f32) | B (N*64 f32)
    char* ws = (char*)d_ws;
    float* inv = (float*)ws;
    float* A = (float*)(ws + 512 * 1024);
    float* B = A + (size_t)N_NODES * 64;

    const int T = 256;
    // Degree / normalization.
    deg_init_kernel<<<(N_NODES + T - 1) / T, T, 0, stream>>>((unsigned*)inv);
    deg_count_kernel<<<(N_EDGES + T - 1) / T, T, 0, stream>>>(dst, (unsigned*)inv);
    inv_from_deg_kernel<<<(N_NODES + T - 1) / T, T, 0, stream>>>(inv);

    // ---- Layer 1: A = (x @ W1) * inv ; B = scatter(A) ; B = relu(inv*(B+A)+b1)
    gemm_scale_kernel<IN_C>
        <<<(N_NODES + 3) / 4, 256, 0, stream>>>(x, W1, inv, A, N_NODES);
    hipMemsetAsync(B, 0, (size_t)N_NODES * 64 * sizeof(float), stream);
    agg_kernel<<<(N_EDGES + 3) / 4, 256, 0, stream>>>(src, dst, A, B);
    finalize_kernel<<<(N_NODES * 64 + T - 1) / T, T, 0, stream>>>(B, A, inv, b1);

    // ---- Layer 2: A = (B @ W2) * inv ; B = scatter(A) ; B = relu(inv*(B+A)+b2)
    gemm_scale_kernel<HID_C>
        <<<(N_NODES + 3) / 4, 256, 0, stream>>>(B, W2, inv, A, N_NODES);
    hipMemsetAsync(B, 0, (size_t)N_NODES * 64 * sizeof(float), stream);
    agg_kernel<<<(N_EDGES + 3) / 4, 256, 0, stream>>>(src, dst, A, B);
    finalize_kernel<<<(N_NODES * 64 + T - 1) / T, T, 0, stream>>>(B, A, inv, b2);

    // ---- Classifier: out = B @ Wf + bf
    final_gemm_kernel<<<(N_NODES + 7) / 8, 320, 0, stream>>>(B, Wf, bf, out, N_NODES);
}

// Round 3
// 773.868 us; speedup vs baseline: 1.4275x; 1.4275x over previous
//
#include <hip/hip_runtime.h>
#include <hip/hip_bf16.h>

// Problem constants (fixed by the reference).
constexpr int N_NODES = 100000;
constexpr int N_EDGES = 1600000;
constexpr int IN_C  = 128;
constexpr int HID_C = 64;   // == OUT_C
constexpr int NUM_CLASSES = 40;

// ---------------------------------------------------------------- degree ----
__global__ void deg_count_kernel(const int* __restrict__ dst, unsigned* __restrict__ deg) {
    int e = blockIdx.x * blockDim.x + threadIdx.x;
    if (e < N_EDGES) atomicAdd(&deg[dst[e]], 1u);
}

// Single-block exclusive scan over deg[N] -> rowptr[N+1]; also writes
// inv[i] = rsqrt(deg+1) (self-loop) and resets deg[i] to the fill cursor.
__global__ void scan_kernel(unsigned* __restrict__ deg, unsigned* __restrict__ rowptr,
                            float* __restrict__ inv) {
    __shared__ unsigned part[1024];
    int t = threadIdx.x;
    constexpr int CH = (N_NODES + 1023) / 1024;   // 98
    int lo = t * CH;
    int hi = min(lo + CH, N_NODES);
    unsigned s = 0;
    for (int i = lo; i < hi; ++i) s += deg[i];
    part[t] = s;
    __syncthreads();
    for (int off = 1; off < 1024; off <<= 1) {
        unsigned u = 0;
        if (t >= off) u = part[t - off];
        __syncthreads();
        if (t >= off) part[t] += u;
        __syncthreads();
    }
    unsigned run = (t > 0) ? part[t - 1] : 0u;
    for (int i = lo; i < hi; ++i) {
        unsigned d = deg[i];
        rowptr[i] = run;
        deg[i]    = run;                       // becomes fill cursor
        inv[i]    = rsqrtf((float)(d + 1u));   // +1 self-loop
        run += d;
    }
    if (t == 1023) rowptr[N_NODES] = part[1023];
}

__global__ void fill_kernel(const int* __restrict__ src, const int* __restrict__ dst,
                            unsigned* __restrict__ cursor, unsigned* __restrict__ csr_src) {
    int e = blockIdx.x * blockDim.x + threadIdx.x;
    if (e >= N_EDGES) return;
    unsigned pos = atomicAdd(&cursor[dst[e]], 1u);
    csr_src[pos] = (unsigned)src[e];
}

// -------------------------------------------------- GEMM (X@W)*inv -> out ---
// X: [n, K] f32 row-major, W: [K, 64] f32 row-major, out[nn] = (X@W)[nn]*inv[nn].
// Block: 256 threads, tile 64 rows x 64 cols, each thread 4x4 outputs.
// X staged TRANSPOSED in LDS (Xs[k][row], stride 68) so the A-fragment is a
// single ds_read_b128; W staged k-major so B-fragment is ds_read_b128 too.
template <int K>
__global__ __launch_bounds__(256) void gemm_scale_kernel(
        const float* __restrict__ X, const float* __restrict__ W,
        const float* __restrict__ inv, float* __restrict__ out, int n) {
    constexpr int C = 64;
    __shared__ float Ws[K * C];
    __shared__ float Xs[64][68];   // [k in chunk][row]; stride 68 keeps 16B align
    int t = threadIdx.x;
    int n0 = blockIdx.x * 64;
    for (int i = t; i < K * C / 4; i += 256)
        ((float4*)Ws)[i] = ((const float4*)W)[i];
    int cg = t & 15;          // col group: cols cg*4..+3
    int rg = t >> 4;          // row group: rows rg*4..+3
    float4 a0 = {0,0,0,0}, a1 = {0,0,0,0}, a2 = {0,0,0,0}, a3 = {0,0,0,0};
    for (int kb = 0; kb < K; kb += 64) {
        __syncthreads();
        for (int i = t; i < 1024; i += 256) {     // 64 rows x 16 float4
            int row = i >> 4, kc = i & 15;
            int nn = n0 + row;
            float4 v = {0,0,0,0};
            if (nn < n) v = *(const float4*)&X[(size_t)nn * K + kb + kc * 4];
            Xs[kc * 4 + 0][row] = v.x;
            Xs[kc * 4 + 1][row] = v.y;
            Xs[kc * 4 + 2][row] = v.z;
            Xs[kc * 4 + 3][row] = v.w;
        }
        __syncthreads();
#pragma unroll 8
        for (int k = 0; k < 64; ++k) {
            float4 b = *(const float4*)&Ws[(kb + k) * C + cg * 4];
            float4 a = *(const float4*)&Xs[k][rg * 4];
            a0.x += a.x * b.x; a0.y += a.x * b.y; a0.z += a.x * b.z; a0.w += a.x * b.w;
            a1.x += a.y * b.x; a1.y += a.y * b.y; a1.z += a.y * b.z; a1.w += a.y * b.w;
            a2.x += a.z * b.x; a2.y += a.z * b.y; a2.z += a.z * b.z; a2.w += a.z * b.w;
            a3.x += a.w * b.x; a3.y += a.w * b.y; a3.z += a.w * b.z; a3.w += a.w * b.w;
        }
    }
    float4 accs[4] = {a0, a1, a2, a3};
#pragma unroll
    for (int i = 0; i < 4; ++i) {
        int nn = n0 + rg * 4 + i;
        if (nn < n) {
            float s = inv[nn];
            float4 r = accs[i];
            r.x *= s; r.y *= s; r.z *= s; r.w *= s;
            *(float4*)&out[(size_t)nn * C + cg * 4] = r;
        }
    }
}

// ---------------------------------------- fused gather-aggregate + epilogue -
// One wave per node: out[d] = relu(inv[d] * (sum_{s in N(d)} hs[s] + hs[d]) + b)
// Quarter-wave split: quarter q handles edges j = beg+q, beg+q+4, ...;
// lane covers channels cl*4..cl*4+3 as float4; cross-quarter shfl reduce.
__global__ __launch_bounds__(256) void agg_fused_kernel(
        const unsigned* __restrict__ rowptr, const unsigned* __restrict__ csr_src,
        const float* __restrict__ hs, const float* __restrict__ inv,
        const float* __restrict__ bias, float* __restrict__ out) {
    int node = blockIdx.x * 4 + (threadIdx.x >> 6);
    int lane = threadIdx.x & 63;
    int q  = lane >> 4;
    int cl = lane & 15;
    unsigned beg = rowptr[node], end = rowptr[node + 1];
    float ax = 0.f, ay = 0.f, az = 0.f, aw = 0.f;
    for (unsigned j = beg + q; j < end; j += 4) {
        unsigned s = csr_src[j];
        const float4 v = *(const float4*)&hs[(size_t)s * 64 + cl * 4];
        ax += v.x; ay += v.y; az += v.z; aw += v.w;
    }
    ax += __shfl_xor(ax, 16); ay += __shfl_xor(ay, 16);
    az += __shfl_xor(az, 16); aw += __shfl_xor(aw, 16);
    ax += __shfl_xor(ax, 32); ay += __shfl_xor(ay, 32);
    az += __shfl_xor(az, 32); aw += __shfl_xor(aw, 32);
    if (q == 0) {
        const float4 self = *(const float4*)&hs[(size_t)node * 64 + cl * 4];
        const float4 bv   = *(const float4*)&bias[cl * 4];
        float s = inv[node];
        float4 r;
        r.x = fmaxf(s * (ax + self.x) + bv.x, 0.f);
        r.y = fmaxf(s * (ay + self.y) + bv.y, 0.f);
        r.z = fmaxf(s * (az + self.z) + bv.z, 0.f);
        r.w = fmaxf(s * (aw + self.w) + bv.w, 0.f);
        *(float4*)&out[(size_t)node * 64 + cl * 4] = r;
    }
}

// ---------------------------------------------- final classifier GEMM -------
// out[n, 40] = H[n, 64] @ Wf[64, 40] + bf.  Block 320, tile 128 rows x 40 cols,
// each thread 4 rows x 4 cols.
__global__ __launch_bounds__(320) void final_gemm_kernel(
        const float* __restrict__ H, const float* __restrict__ Wf,
        const float* __restrict__ bfv, float* __restrict__ out, int n) {
    constexpr int CK = 64, J = 40;
    __shared__ float Ws[CK * J];
    __shared__ float Hs[CK][132];   // [k][row 0..127], stride 132 (16B align)
    int t = threadIdx.x;
    int n0 = blockIdx.x * 128;
    for (int i = t; i < CK * J / 4; i += 320)
        ((float4*)Ws)[i] = ((const float4*)Wf)[i];
    for (int i = t; i < 128 * 16; i += 320) {   // 128 rows x 16 float4
        int row = i >> 4, kc = i & 15;
        int nn = n0 + row;
        float4 v = {0,0,0,0};
        if (nn < n) v = *(const float4*)&H[(size_t)nn * 64 + kc * 4];
        Hs[kc * 4 + 0][row] = v.x;
        Hs[kc * 4 + 1][row] = v.y;
        Hs[kc * 4 + 2][row] = v.z;
        Hs[kc * 4 + 3][row] = v.w;
    }
    __syncthreads();
    int cg = t % 10;          // cols cg*4..+3 (of 40)
    int rg = t / 10;          // rows rg*4..+3 (0..31 -> 128 rows)
    float4 a0 = {0,0,0,0}, a1 = {0,0,0,0}, a2 = {0,0,0,0}, a3 = {0,0,0,0};
#pragma unroll 8
    for (int k = 0; k < CK; ++k) {
        float4 b = *(const float4*)&Ws[k * J + cg * 4];
        float4 a = *(const float4*)&Hs[k][rg * 4];
        a0.x += a.x * b.x; a0.y += a.x * b.y; a0.z += a.x * b.z; a0.w += a.x * b.w;
        a1.x += a.y * b.x; a1.y += a.y * b.y; a1.z += a.y * b.z; a1.w += a.y * b.w;
        a2.x += a.z * b.x; a2.y += a.z * b.y; a2.z += a.z * b.z; a2.w += a.z * b.w;
        a3.x += a.w * b.x; a3.y += a.w * b.y; a3.z += a.w * b.z; a3.w += a.w * b.w;
    }
    float4 bv = *(const float4*)&bfv[cg * 4];
    float4 accs[4] = {a0, a1, a2, a3};
#pragma unroll
    for (int i = 0; i < 4; ++i) {
        int nn = n0 + rg * 4 + i;
        if (nn < n) {
            float4 r = accs[i];
            r.x += bv.x; r.y += bv.y; r.z += bv.z; r.w += bv.w;
            *(float4*)&out[(size_t)nn * J + cg * 4] = r;
        }
    }
}

// ---------------------------------------------------------------- launch ----
extern "C" void kernel_launch(void* const* d_in, const int* in_sizes, int n_in,
                              void* d_out, int out_size, void* d_ws, size_t ws_size,
                              hipStream_t stream) {
    const float* x  = (const float*)d_in[0];
    const int*   ei = (const int*)d_in[1];
    const float* W1 = (const float*)d_in[2];
    const float* b1 = (const float*)d_in[3];
    const float* W2 = (const float*)d_in[4];
    const float* b2 = (const float*)d_in[5];
    const float* Wf = (const float*)d_in[6];
    const float* bf = (const float*)d_in[7];
    float* out = (float*)d_out;

    const int* src = ei;            // edge_index[0, :]
    const int* dst = ei + N_EDGES;  // edge_index[1, :]

    // Workspace layout (bytes):
    // deg/cursor: [0, 400000) | rowptr: [400000, 800004) | inv: [800064, 1200064)
    // csr_src: [1200064, 7600064) | A: [7600128, +25.6M) | B: [33200128, +25.6M)
    char* ws = (char*)d_ws;
    unsigned* deg     = (unsigned*)(ws + 0);
    unsigned* rowptr  = (unsigned*)(ws + 400000);
    float*    inv     = (float*)   (ws + 800064);
    unsigned* csr_src = (unsigned*)(ws + 1200064);
    float*    A       = (float*)   (ws + 7600128);
    float*    B       = (float*)   (ws + 33200128);

    const int T = 256;
    const int EB = (N_EDGES + T - 1) / T;

    // ---- CSR build (per-call; no state may survive between calls)
    hipMemsetAsync(deg, 0, N_NODES * sizeof(unsigned), stream);
    deg_count_kernel<<<EB, T, 0, stream>>>(dst, deg);
    scan_kernel<<<1, 1024, 0, stream>>>(deg, rowptr, inv);
    fill_kernel<<<EB, T, 0, stream>>>(src, dst, deg, csr_src);

    // ---- Layer 1
    gemm_scale_kernel<IN_C><<<(N_NODES + 63) / 64, 256, 0, stream>>>(x, W1, inv, A, N_NODES);
    agg_fused_kernel<<<N_NODES / 4, 256, 0, stream>>>(rowptr, csr_src, A, inv, b1, B);

    // ---- Layer 2
    gemm_scale_kernel<HID_C><<<(N_NODES + 63) / 64, 256, 0, stream>>>(B, W2, inv, A, N_NODES);
    agg_fused_kernel<<<N_NODES / 4, 256, 0, stream>>>(rowptr, csr_src, A, inv, b2, B);

    // ---- Classifier
    final_gemm_kernel<<<(N_NODES + 127) / 128, 320, 0, stream>>>(B, Wf, bf, out, N_NODES);
}

// Round 4
// 508.206 us; speedup vs baseline: 2.1737x; 1.5227x over previous
//
#include <hip/hip_runtime.h>
#include <hip/hip_bf16.h>

// Problem constants (fixed by the reference).
constexpr int N_NODES = 100000;
constexpr int N_EDGES = 1600000;
constexpr int IN_C  = 128;
constexpr int HID_C = 64;   // == OUT_C
constexpr int NUM_CLASSES = 40;

constexpr int SCAN_B = 256;
constexpr int NBLK = (N_NODES + SCAN_B - 1) / SCAN_B;   // 391

// ---------------------------------------------------------------- degree ----
__global__ void deg_count_kernel(const int* __restrict__ dst, unsigned* __restrict__ deg) {
    int e = blockIdx.x * blockDim.x + threadIdx.x;
    if (e < N_EDGES) atomicAdd(&deg[dst[e]], 1u);
}

// ------------------------------------------------- parallel 3-phase scan ----
// Phase 1: per-block sums of deg (391 blocks x 256).
__global__ __launch_bounds__(SCAN_B) void block_sum_kernel(
        const unsigned* __restrict__ deg, unsigned* __restrict__ partials) {
    __shared__ unsigned s[SCAN_B];
    int t = threadIdx.x;
    int i = blockIdx.x * SCAN_B + t;
    s[t] = (i < N_NODES) ? deg[i] : 0u;
    __syncthreads();
    for (int off = SCAN_B / 2; off > 0; off >>= 1) {
        if (t < off) s[t] += s[t + off];
        __syncthreads();
    }
    if (t == 0) partials[blockIdx.x] = s[0];
}

// Phase 2: single block scans the 391 partials (exclusive); writes rowptr[N].
__global__ __launch_bounds__(512) void scan_partials_kernel(
        unsigned* __restrict__ partials, unsigned* __restrict__ rowptr) {
    __shared__ unsigned s[512];
    int t = threadIdx.x;
    unsigned v = (t < NBLK) ? partials[t] : 0u;
    s[t] = v;
    __syncthreads();
    for (int off = 1; off < 512; off <<= 1) {
        unsigned u = (t >= off) ? s[t - off] : 0u;
        __syncthreads();
        s[t] += u;
        __syncthreads();
    }
    if (t < NBLK) partials[t] = s[t] - v;          // exclusive prefix
    if (t == NBLK - 1) rowptr[N_NODES] = s[t];     // total edge count
}

// Phase 3: in-block exclusive scan + block base; writes rowptr, cursor, inv.
__global__ __launch_bounds__(SCAN_B) void scan_final_kernel(
        unsigned* __restrict__ deg, const unsigned* __restrict__ partials,
        unsigned* __restrict__ rowptr, float* __restrict__ inv) {
    __shared__ unsigned s[SCAN_B];
    int t = threadIdx.x;
    int i = blockIdx.x * SCAN_B + t;
    unsigned d = (i < N_NODES) ? deg[i] : 0u;
    s[t] = d;
    __syncthreads();
    for (int off = 1; off < SCAN_B; off <<= 1) {
        unsigned u = (t >= off) ? s[t - off] : 0u;
        __syncthreads();
        s[t] += u;
        __syncthreads();
    }
    if (i < N_NODES) {
        unsigned pos = partials[blockIdx.x] + s[t] - d;   // exclusive
        rowptr[i] = pos;
        deg[i]    = pos;                        // fill cursor
        inv[i]    = rsqrtf((float)(d + 1u));    // +1 self-loop
    }
}

__global__ void fill_kernel(const int* __restrict__ src, const int* __restrict__ dst,
                            unsigned* __restrict__ cursor, unsigned* __restrict__ csr_src) {
    int e = blockIdx.x * blockDim.x + threadIdx.x;
    if (e >= N_EDGES) return;
    unsigned pos = atomicAdd(&cursor[dst[e]], 1u);
    csr_src[pos] = (unsigned)src[e];
}

// -------------------------------------------------- GEMM (X@W)*inv -> out ---
// X: [n, K] f32 row-major, W: [K, 64] f32 row-major, out[nn] = (X@W)[nn]*inv[nn].
// Block: 256 threads, tile 64 rows x 64 cols, each thread 4x4 outputs.
template <int K>
__global__ __launch_bounds__(256) void gemm_scale_kernel(
        const float* __restrict__ X, const float* __restrict__ W,
        const float* __restrict__ inv, float* __restrict__ out, int n) {
    constexpr int C = 64;
    __shared__ float Ws[K * C];
    __shared__ float Xs[64][68];   // [k in chunk][row]; stride 68 keeps 16B align
    int t = threadIdx.x;
    int n0 = blockIdx.x * 64;
    for (int i = t; i < K * C / 4; i += 256)
        ((float4*)Ws)[i] = ((const float4*)W)[i];
    int cg = t & 15;          // col group: cols cg*4..+3
    int rg = t >> 4;          // row group: rows rg*4..+3
    float4 a0 = {0,0,0,0}, a1 = {0,0,0,0}, a2 = {0,0,0,0}, a3 = {0,0,0,0};
    for (int kb = 0; kb < K; kb += 64) {
        __syncthreads();
        for (int i = t; i < 1024; i += 256) {     // 64 rows x 16 float4
            int row = i >> 4, kc = i & 15;
            int nn = n0 + row;
            float4 v = {0,0,0,0};
            if (nn < n) v = *(const float4*)&X[(size_t)nn * K + kb + kc * 4];
            Xs[kc * 4 + 0][row] = v.x;
            Xs[kc * 4 + 1][row] = v.y;
            Xs[kc * 4 + 2][row] = v.z;
            Xs[kc * 4 + 3][row] = v.w;
        }
        __syncthreads();
#pragma unroll 8
        for (int k = 0; k < 64; ++k) {
            float4 b = *(const float4*)&Ws[(kb + k) * C + cg * 4];
            float4 a = *(const float4*)&Xs[k][rg * 4];
            a0.x += a.x * b.x; a0.y += a.x * b.y; a0.z += a.x * b.z; a0.w += a.x * b.w;
            a1.x += a.y * b.x; a1.y += a.y * b.y; a1.z += a.y * b.z; a1.w += a.y * b.w;
            a2.x += a.z * b.x; a2.y += a.z * b.y; a2.z += a.z * b.z; a2.w += a.z * b.w;
            a3.x += a.w * b.x; a3.y += a.w * b.y; a3.z += a.w * b.z; a3.w += a.w * b.w;
        }
    }
    float4 accs[4] = {a0, a1, a2, a3};
#pragma unroll
    for (int i = 0; i < 4; ++i) {
        int nn = n0 + rg * 4 + i;
        if (nn < n) {
            float s = inv[nn];
            float4 r = accs[i];
            r.x *= s; r.y *= s; r.z *= s; r.w *= s;
            *(float4*)&out[(size_t)nn * C + cg * 4] = r;
        }
    }
}

// ---------------------------------------- fused gather-aggregate + epilogue -
// One wave per node: out[d] = relu(inv[d] * (sum_{s in N(d)} hs[s] + hs[d]) + b)
__global__ __launch_bounds__(256) void agg_fused_kernel(
        const unsigned* __restrict__ rowptr, const unsigned* __restrict__ csr_src,
        const float* __restrict__ hs, const float* __restrict__ inv,
        const float* __restrict__ bias, float* __restrict__ out) {
    int node = blockIdx.x * 4 + (threadIdx.x >> 6);
    int lane = threadIdx.x & 63;
    int q  = lane >> 4;
    int cl = lane & 15;
    unsigned beg = rowptr[node], end = rowptr[node + 1];
    float ax = 0.f, ay = 0.f, az = 0.f, aw = 0.f;
    for (unsigned j = beg + q; j < end; j += 4) {
        unsigned s = csr_src[j];
        const float4 v = *(const float4*)&hs[(size_t)s * 64 + cl * 4];
        ax += v.x; ay += v.y; az += v.z; aw += v.w;
    }
    ax += __shfl_xor(ax, 16); ay += __shfl_xor(ay, 16);
    az += __shfl_xor(az, 16); aw += __shfl_xor(aw, 16);
    ax += __shfl_xor(ax, 32); ay += __shfl_xor(ay, 32);
    az += __shfl_xor(az, 32); aw += __shfl_xor(aw, 32);
    if (q == 0) {
        const float4 self = *(const float4*)&hs[(size_t)node * 64 + cl * 4];
        const float4 bv   = *(const float4*)&bias[cl * 4];
        float s = inv[node];
        float4 r;
        r.x = fmaxf(s * (ax + self.x) + bv.x, 0.f);
        r.y = fmaxf(s * (ay + self.y) + bv.y, 0.f);
        r.z = fmaxf(s * (az + self.z) + bv.z, 0.f);
        r.w = fmaxf(s * (aw + self.w) + bv.w, 0.f);
        *(float4*)&out[(size_t)node * 64 + cl * 4] = r;
    }
}

// ---------------------------------------------- final classifier GEMM -------
// out[n, 40] = H[n, 64] @ Wf[64, 40] + bf.  Block 320, tile 128 rows x 40 cols.
__global__ __launch_bounds__(320) void final_gemm_kernel(
        const float* __restrict__ H, const float* __restrict__ Wf,
        const float* __restrict__ bfv, float* __restrict__ out, int n) {
    constexpr int CK = 64, J = 40;
    __shared__ float Ws[CK * J];
    __shared__ float Hs[CK][132];   // [k][row 0..127], stride 132 (16B align)
    int t = threadIdx.x;
    int n0 = blockIdx.x * 128;
    for (int i = t; i < CK * J / 4; i += 320)
        ((float4*)Ws)[i] = ((const float4*)Wf)[i];
    for (int i = t; i < 128 * 16; i += 320) {   // 128 rows x 16 float4
        int row = i >> 4, kc = i & 15;
        int nn = n0 + row;
        float4 v = {0,0,0,0};
        if (nn < n) v = *(const float4*)&H[(size_t)nn * 64 + kc * 4];
        Hs[kc * 4 + 0][row] = v.x;
        Hs[kc * 4 + 1][row] = v.y;
        Hs[kc * 4 + 2][row] = v.z;
        Hs[kc * 4 + 3][row] = v.w;
    }
    __syncthreads();
    int cg = t % 10;          // cols cg*4..+3 (of 40)
    int rg = t / 10;          // rows rg*4..+3 (0..31 -> 128 rows)
    float4 a0 = {0,0,0,0}, a1 = {0,0,0,0}, a2 = {0,0,0,0}, a3 = {0,0,0,0};
#pragma unroll 8
    for (int k = 0; k < CK; ++k) {
        float4 b = *(const float4*)&Ws[k * J + cg * 4];
        float4 a = *(const float4*)&Hs[k][rg * 4];
        a0.x += a.x * b.x; a0.y += a.x * b.y; a0.z += a.x * b.z; a0.w += a.x * b.w;
        a1.x += a.y * b.x; a1.y += a.y * b.y; a1.z += a.y * b.z; a1.w += a.y * b.w;
        a2.x += a.z * b.x; a2.y += a.z * b.y; a2.z += a.z * b.z; a2.w += a.z * b.w;
        a3.x += a.w * b.x; a3.y += a.w * b.y; a3.z += a.w * b.z; a3.w += a.w * b.w;
    }
    float4 bv = *(const float4*)&bfv[cg * 4];
    float4 accs[4] = {a0, a1, a2, a3};
#pragma unroll
    for (int i = 0; i < 4; ++i) {
        int nn = n0 + rg * 4 + i;
        if (nn < n) {
            float4 r = accs[i];
            r.x += bv.x; r.y += bv.y; r.z += bv.z; r.w += bv.w;
            *(float4*)&out[(size_t)nn * J + cg * 4] = r;
        }
    }
}

// ---------------------------------------------------------------- launch ----
extern "C" void kernel_launch(void* const* d_in, const int* in_sizes, int n_in,
                              void* d_out, int out_size, void* d_ws, size_t ws_size,
                              hipStream_t stream) {
    const float* x  = (const float*)d_in[0];
    const int*   ei = (const int*)d_in[1];
    const float* W1 = (const float*)d_in[2];
    const float* b1 = (const float*)d_in[3];
    const float* W2 = (const float*)d_in[4];
    const float* b2 = (const float*)d_in[5];
    const float* Wf = (const float*)d_in[6];
    const float* bf = (const float*)d_in[7];
    float* out = (float*)d_out;

    const int* src = ei;            // edge_index[0, :]
    const int* dst = ei + N_EDGES;  // edge_index[1, :]

    // Workspace layout (bytes):
    // deg/cursor: [0, 400000) | rowptr: [400000, 800004) | inv: [800064, 1200064)
    // partials: [1200064, 1201628) | csr_src: [1201664, 7601664)
    // A: [7601664, +25.6M) | B: [33201664, +25.6M)
    char* ws = (char*)d_ws;
    unsigned* deg      = (unsigned*)(ws + 0);
    unsigned* rowptr   = (unsigned*)(ws + 400000);
    float*    inv      = (float*)   (ws + 800064);
    unsigned* partials = (unsigned*)(ws + 1200064);
    unsigned* csr_src  = (unsigned*)(ws + 1201664);
    float*    A        = (float*)   (ws + 7601664);
    float*    B        = (float*)   (ws + 33201664);

    const int T = 256;
    const int EB = (N_EDGES + T - 1) / T;

    // ---- CSR build (per-call; no state may survive between calls)
    hipMemsetAsync(deg, 0, N_NODES * sizeof(unsigned), stream);
    deg_count_kernel<<<EB, T, 0, stream>>>(dst, deg);
    block_sum_kernel<<<NBLK, SCAN_B, 0, stream>>>(deg, partials);
    scan_partials_kernel<<<1, 512, 0, stream>>>(partials, rowptr);
    scan_final_kernel<<<NBLK, SCAN_B, 0, stream>>>(deg, partials, rowptr, inv);
    fill_kernel<<<EB, T, 0, stream>>>(src, dst, deg, csr_src);

    // ---- Layer 1
    gemm_scale_kernel<IN_C><<<(N_NODES + 63) / 64, 256, 0, stream>>>(x, W1, inv, A, N_NODES);
    agg_fused_kernel<<<N_NODES / 4, 256, 0, stream>>>(rowptr, csr_src, A, inv, b1, B);

    // ---- Layer 2
    gemm_scale_kernel<HID_C><<<(N_NODES + 63) / 64, 256, 0, stream>>>(B, W2, inv, A, N_NODES);
    agg_fused_kernel<<<N_NODES / 4, 256, 0, stream>>>(rowptr, csr_src, A, inv, b2, B);

    // ---- Classifier
    final_gemm_kernel<<<(N_NODES + 127) / 128, 320, 0, stream>>>(B, Wf, bf, out, N_NODES);
}